// Round 1
// 331.925 us; speedup vs baseline: 1.3887x; 1.3887x over previous
//
#include <hip/hip_runtime.h>
#include <math.h>

// Problem constants (fixed by setup_inputs)
#define BB 16
#define CC 96
#define HH 112
#define WW 112
#define HO 56
#define WO 56
#define LL (HO*WO)       // 3136
#define CO 192
#define CKD 384          // C*K
#define NPIX (BB*LL)     // 50176
#define PADROW 388       // LDS row pad for sampled[32][384] (stride 1552B: 2-way on frag reads)

// ws layout (floats): ssum=+16 (192), ssqs=+208 (192), scale=+400, shift=+592
#define WS_SSUM  16
#define WS_SSQS  208
#define WS_SCALE 400
#define WS_SHIFT 592
// bf16-swizzled w_def planes at byte offset 4096 (each 73728 ushorts = 147456 B)
#define WS_B_OFF 4096
#define B_ELEMS  73728

typedef short bf16x8 __attribute__((ext_vector_type(8)));
typedef float f32x4  __attribute__((ext_vector_type(4)));

// Split 8 fp32 into hi/lo bf16 planes (truncation; lo captures the remainder,
// combined rel err ~2^-17)
__device__ __forceinline__ void split8(const float4 a0, const float4 a1,
                                       bf16x8& hi, bf16x8& lo)
{
    float f[8] = {a0.x, a0.y, a0.z, a0.w, a1.x, a1.y, a1.z, a1.w};
    #pragma unroll
    for (int j = 0; j < 8; ++j) {
        unsigned bits = __float_as_uint(f[j]);
        float fh = __uint_as_float(bits & 0xFFFF0000u);
        float fl = f[j] - fh;
        hi[j] = (short)(bits >> 16);
        lo[j] = (short)(__float_as_uint(fl) >> 16);
    }
}

// -------- K0: zero the stats accumulators --------
__global__ void k_zero(float* __restrict__ ws) {
    int t = threadIdx.x;
    if (t < 384) ws[WS_SSUM + t] = 0.f;
}

// -------- K-prep: w_def fp32 -> frag-ordered bf16 hi/lo planes --------
// layout: idx = ((ntg*12 + ks)*64 + lane)*8 + j  maps to  B[k][n] = w_def[n][k]
// with n = ntg*16 + (lane&15), k = ks*32 + (lane>>4)*8 + j
__global__ void k_prep(const float* __restrict__ w_def,
                       unsigned short* __restrict__ bhi,
                       unsigned short* __restrict__ blo)
{
    int t = blockIdx.x * 256 + threadIdx.x;
    if (t >= 12 * 12 * 64) return;
    int ln  = t & 63;
    int ks  = (t >> 6) % 12;
    int ntg = t / (64 * 12);
    int n  = ntg * 16 + (ln & 15);
    int k0 = ks * 32 + (ln >> 4) * 8;
    const float* wp = w_def + (size_t)n * CKD + k0;
    #pragma unroll
    for (int j = 0; j < 8; ++j) {
        float f = wp[j];
        unsigned bits = __float_as_uint(f);
        float fh = __uint_as_float(bits & 0xFFFF0000u);
        float fl = f - fh;
        bhi[t * 8 + j] = (unsigned short)(bits >> 16);
        blo[t * 8 + j] = (unsigned short)(__float_as_uint(fl) >> 16);
    }
}

// ---- K2: fused offset-conv + bilinear sample + MFMA GEMM + stats + y store ----
template<bool PREP>
__global__ __launch_bounds__(256) void k_main(
    const float* __restrict__ x,      // [B][C][H][W]
    const float* __restrict__ w_off,  // [8][C][2][2]
    const float* __restrict__ b_off,  // [8]
    const float* __restrict__ w_def,  // [CO][C][4] fp32 (fallback B source)
    const unsigned short* __restrict__ bhi,  // frag-ordered bf16 hi plane
    const unsigned short* __restrict__ blo,  // frag-ordered bf16 lo plane
    float* __restrict__ yout,         // d_out fp32 [B][L][CO] (pre-BN y)
    float* __restrict__ ws)
{
    __shared__ float sm[32 * PADROW];    // 49664 B
    __shared__ float soff[32 * 8];       // [pix][och] conv-offset outputs
    const int tid = threadIdx.x;
    const int b  = blockIdx.y;
    const int l0 = blockIdx.x * 32;

    const int pair = tid >> 1;   // 0..127 = (pix, k)
    const int half = tid & 1;
    const int pix = pair >> 2;
    const int k   = pair & 3;
    const int l   = l0 + pix;
    const int oy = l / WO, ox = l % WO;
    const int iy = oy * 2, ix = ox * 2;

    // ---- Phase 0: offset conv. thread computes channel och=2k+half ----
    {
        const int och = 2 * k + half;
        float d = b_off[och];
        const float* xb = x + ((size_t)b * CC) * (HH * WW) + (size_t)iy * WW + ix;
        const float* wb = w_off + (size_t)och * (CC * 4);
        for (int c = 0; c < CC; ++c) {
            const float* xp = xb + (size_t)c * (HH * WW);
            float4 a = *(const float4*)(wb + c * 4);
            d += xp[0] * a.x + xp[1] * a.y + xp[WW] * a.z + xp[WW + 1] * a.w;
        }
        soff[pix * 8 + och] = d;
    }
    __syncthreads();

    // ---- Phase A: bilinear sampling 32 pixels x 384 (c*4+k) into LDS ----
    {
        const int ky = k >> 1, kx = k & 1;
        float fy = (float)(iy + ky) + soff[pix * 8 + 2 * k];
        float fx = (float)(ix + kx) + soff[pix * 8 + 2 * k + 1];
        float y0f = floorf(fy), x0f = floorf(fx);
        int y0 = (int)y0f, x0 = (int)x0f;
        float wy1 = fy - y0f, wx1 = fx - x0f;
        float wy0 = 1.f - wy1, wx0 = 1.f - wx1;
        int y1 = y0 + 1, x1 = x0 + 1;
        bool vy0 = (y0 >= 0) && (y0 <= HH - 1);
        bool vy1 = (y1 >= 0) && (y1 <= HH - 1);
        bool vx0 = (x0 >= 0) && (x0 <= WW - 1);
        bool vx1 = (x1 >= 0) && (x1 <= WW - 1);
        int cy0 = min(max(y0, 0), HH - 1), cy1 = min(max(y1, 0), HH - 1);
        int cx0 = min(max(x0, 0), WW - 1), cx1 = min(max(x1, 0), WW - 1);
        float w00 = (vy0 && vx0) ? wy0 * wx0 : 0.f;
        float w01 = (vy0 && vx1) ? wy0 * wx1 : 0.f;
        float w10 = (vy1 && vx0) ? wy1 * wx0 : 0.f;
        float w11 = (vy1 && vx1) ? wy1 * wx1 : 0.f;
        int i00 = cy0 * WW + cx0, i01 = cy0 * WW + cx1;
        int i10 = cy1 * WW + cx0, i11 = cy1 * WW + cx1;
        const int cbeg = half * 48;
        const float* xc = x + (size_t)b * CC * (HH * WW) + (size_t)cbeg * (HH * WW);
        float* dst = &sm[pix * PADROW + k];
        for (int c = 0; c < 48; ++c) {
            float v = w00 * xc[i00] + w01 * xc[i01]
                    + w10 * xc[i10] + w11 * xc[i11];
            dst[(cbeg + c) * 4] = v;
            xc += HH * WW;
        }
    }
    __syncthreads();

    // ---- Phase B: MFMA GEMM [32 x 384] * [384 x 192], bf16 hi/lo split ----
    // wave w owns output cols w*48..w*48+47 (3 n-tiles), both m-tiles.
    const int ln = tid & 63;
    const int w  = tid >> 6;
    const int row0 = ln & 15;        // A row / B col within tile
    const int kg   = ln >> 4;        // k-group (8 contiguous k)

    f32x4 acc[2][3];
    #pragma unroll
    for (int mt = 0; mt < 2; ++mt)
        #pragma unroll
        for (int nt = 0; nt < 3; ++nt)
            acc[mt][nt] = (f32x4){0.f, 0.f, 0.f, 0.f};

    for (int ks = 0; ks < 12; ++ks) {
        bf16x8 ahi[2], alo[2];
        #pragma unroll
        for (int mt = 0; mt < 2; ++mt) {
            const float* ap = &sm[(mt * 16 + row0) * PADROW + ks * 32 + kg * 8];
            float4 a0 = *(const float4*)ap;
            float4 a1 = *(const float4*)(ap + 4);
            split8(a0, a1, ahi[mt], alo[mt]);
        }
        #pragma unroll
        for (int nt = 0; nt < 3; ++nt) {
            bf16x8 vbh, vbl;
            if (PREP) {
                size_t idx = ((size_t)(((w * 3 + nt) * 12 + ks) * 64) + ln) * 8;
                vbh = *(const bf16x8*)(bhi + idx);
                vbl = *(const bf16x8*)(blo + idx);
            } else {
                const float* wp = w_def + (size_t)(w * 48 + nt * 16 + row0) * CKD
                                + ks * 32 + kg * 8;
                float4 b0 = *(const float4*)wp;
                float4 b1 = *(const float4*)(wp + 4);
                split8(b0, b1, vbh, vbl);
            }
            #pragma unroll
            for (int mt = 0; mt < 2; ++mt) {
                acc[mt][nt] = __builtin_amdgcn_mfma_f32_16x16x32_bf16(ahi[mt], vbh, acc[mt][nt], 0, 0, 0);
                acc[mt][nt] = __builtin_amdgcn_mfma_f32_16x16x32_bf16(ahi[mt], vbl, acc[mt][nt], 0, 0, 0);
                acc[mt][nt] = __builtin_amdgcn_mfma_f32_16x16x32_bf16(alo[mt], vbh, acc[mt][nt], 0, 0, 0);
            }
        }
    }
    __syncthreads();

    // ---- Phase C: stage y in LDS, stats, coalesced fp32 store ----
    // C/D layout: col = lane&15, row = (lane>>4)*4 + reg  [HW-verified m89/m91]
    float* ys = sm;  // 32*193 floats, reuse
    #pragma unroll
    for (int mt = 0; mt < 2; ++mt)
        #pragma unroll
        for (int nt = 0; nt < 3; ++nt)
            #pragma unroll
            for (int r = 0; r < 4; ++r) {
                int pp = mt * 16 + kg * 4 + r;
                int o  = w * 48 + nt * 16 + row0;
                ys[pp * 193 + o] = acc[mt][nt][r];
            }
    __syncthreads();

    if (tid < CO) {
        float s = 0.f, q = 0.f;
        #pragma unroll 8
        for (int p = 0; p < 32; ++p) {
            float v = ys[p * 193 + tid];
            s += v; q += v * v;
        }
        atomicAdd(&ws[WS_SSUM + tid], s);
        atomicAdd(&ws[WS_SSQS + tid], q);
    }

    size_t base = ((size_t)b * LL + l0) * CO;
    for (int i = tid; i < 32 * CO; i += 256) {
        int pp = i / CO, o = i % CO;
        yout[base + i] = ys[pp * 193 + o];
    }
}

// ------------- K2.5: per-channel scale/shift from batch stats -------------
__global__ void k_stats(const float* __restrict__ gamma,
                        const float* __restrict__ beta,
                        float* __restrict__ ws)
{
    int o = threadIdx.x;
    if (o < CO) {
        float n = (float)NPIX;
        float mu = ws[WS_SSUM + o] / n;
        float var = ws[WS_SSQS + o] / n - mu * mu;
        float sc = gamma[o] * rsqrtf(fmaxf(var, 0.f) + 1e-5f);
        ws[WS_SCALE + o] = sc;
        ws[WS_SHIFT + o] = beta[o] - mu * sc;
    }
}

// ---------------- K3: in-place fp32 BN + exact GELU over d_out ----------------
__global__ __launch_bounds__(256) void k_bn_gelu(
    float* __restrict__ out,          // fp32, in/out, [B][L][CO]
    const float* __restrict__ ws)
{
    long long gid = (long long)blockIdx.x * 256 + threadIdx.x;
    long long i4 = gid * 4;
    if (i4 >= (long long)NPIX * CO) return;
    int o0 = (int)(i4 % CO);          // 4 | 192 -> quad stays in-channel-run
    float4* p = (float4*)(out + i4);
    float4 v = *p;
    float f[4] = { v.x, v.y, v.z, v.w };
    #pragma unroll
    for (int j = 0; j < 4; ++j) {
        float z = ws[WS_SCALE + o0 + j] * f[j] + ws[WS_SHIFT + o0 + j];
        f[j] = 0.5f * z * (1.f + erff(z * 0.70710678118654752f));
    }
    v.x = f[0]; v.y = f[1]; v.z = f[2]; v.w = f[3];
    *p = v;
}

extern "C" void kernel_launch(void* const* d_in, const int* in_sizes, int n_in,
                              void* d_out, int out_size, void* d_ws, size_t ws_size,
                              hipStream_t stream)
{
    // Bind by size signature (robust to scalar h/w presence):
    const float *x = nullptr, *w_off = nullptr, *b_off = nullptr;
    const float *w_def = nullptr, *gamma = nullptr, *beta = nullptr;
    for (int i = 0; i < n_in; ++i) {
        int s = in_sizes[i];
        if      (s == 19267584) x     = (const float*)d_in[i];
        else if (s == 3072)     w_off = (const float*)d_in[i];
        else if (s == 8)        b_off = (const float*)d_in[i];
        else if (s == 73728)    w_def = (const float*)d_in[i];
        else if (s == 192) { if (!gamma) gamma = (const float*)d_in[i];
                             else        beta  = (const float*)d_in[i]; }
    }
    if (!x || !w_off || !b_off || !w_def || !gamma || !beta) {
        x = (const float*)d_in[0]; w_off = (const float*)d_in[3];
        b_off = (const float*)d_in[4]; w_def = (const float*)d_in[5];
        gamma = (const float*)d_in[6]; beta = (const float*)d_in[7];
    }

    float* ws = (float*)d_ws;                  // stats region
    float* out = (float*)d_out;                // FP32 output

    unsigned short* bhi = (unsigned short*)((char*)d_ws + WS_B_OFF);
    unsigned short* blo = bhi + B_ELEMS;
    bool prep = ws_size >= (size_t)(WS_B_OFF + 2 * B_ELEMS * sizeof(unsigned short));

    k_zero<<<1, 384, 0, stream>>>(ws);
    if (prep) {
        k_prep<<<36, 256, 0, stream>>>(w_def, bhi, blo);
        k_main<true><<<dim3(LL/32, BB), 256, 0, stream>>>(x, w_off, b_off, w_def, bhi, blo, out, ws);
    } else {
        k_main<false><<<dim3(LL/32, BB), 256, 0, stream>>>(x, w_off, b_off, w_def, bhi, blo, out, ws);
    }
    k_stats<<<1, 256, 0, stream>>>(gamma, beta, ws);
    k_bn_gelu<<<dim3((int)(((long long)NPIX*CO/4 + 255) / 256)), 256, 0, stream>>>(out, ws);
}